// Round 5
// baseline (463.369 us; speedup 1.0000x reference)
//
#include <hip/hip_runtime.h>

// DIAGNOSTIC BUILD: body repeated 4x (identical work, same final output) so the
// kernel's own dispatch exceeds the ~160us harness fill dispatches and surfaces
// in the rocprof top-5 with its true counters. K_true = dispatch_dur / 4.
//
// DeltaDequantization: B=1024, T=2048, NB=32, ADAPT_STEP=32, nchunks=64.
// bins[b,:] = quant_bins * S_b (scalar per batch) =>
// out[b,t] = pred_c + S_c * db[t]; db/dc = dot-32s; 64-step scalar scan.

#define TLEN 2048
#define NB 32
#define NCHUNK 64   // TLEN / 32
#define NREP 4      // diagnostic repetition factor

__global__ __launch_bounds__(512, 8) void delta_dequant_kernel(
    const float* __restrict__ x,
    const float* __restrict__ quant_bins,
    const float* __restrict__ change_scales,
    float* __restrict__ out)
{
    __shared__ float s_db[TLEN];
    __shared__ float s_dc[TLEN];
    __shared__ float s_S[NCHUNK];
    __shared__ float s_P[NCHUNK];

    const int b    = blockIdx.x;
    const int tid  = threadIdx.x;
    const int lane = tid & 63;
    const int wid  = tid >> 6;     // wave id 0..7
    const int sub  = lane & 7;     // which float4 of the 32-float row
    const int tg   = lane >> 3;    // timestep within the wave's group of 8

    const float4 qb4 = ((const float4*)quant_bins)[sub];
    const float4 cs4 = ((const float4*)change_scales)[sub];
    const float* __restrict__ xb = x + (size_t)b * (TLEN * NB);

    for (int rep = 0; rep < NREP; ++rep) {
        // ---- Phase 1: db/dc for all 2048 timesteps ----
        for (int k = 0; k < 32; k += 4) {
            const int tbase = k * 64 + wid * 8 + tg;
            float4 v[4];
            #pragma unroll
            for (int u = 0; u < 4; ++u)
                v[u] = ((const float4*)(xb + (size_t)(tbase + u * 64) * NB))[sub];
            #pragma unroll
            for (int u = 0; u < 4; ++u) {
                float db = v[u].x * qb4.x + v[u].y * qb4.y + v[u].z * qb4.z + v[u].w * qb4.w;
                float dc = v[u].x * cs4.x + v[u].y * cs4.y + v[u].z * cs4.z + v[u].w * cs4.w;
                db += __shfl_xor(db, 1); dc += __shfl_xor(dc, 1);
                db += __shfl_xor(db, 2); dc += __shfl_xor(dc, 2);
                db += __shfl_xor(db, 4); dc += __shfl_xor(dc, 4);
                if (sub == 0) { s_db[tbase + u * 64] = db; s_dc[tbase + u * 64] = dc; }
            }
        }
        __syncthreads();

        // ---- Phase 2a: per-chunk means ----
        {
            float4 a4 = ((const float4*)s_db)[tid];
            float4 g4 = ((const float4*)s_dc)[tid];
            float pa = a4.x + a4.y + a4.z + a4.w;
            float pg = g4.x + g4.y + g4.z + g4.w;
            pa += __shfl_xor(pa, 1); pg += __shfl_xor(pg, 1);
            pa += __shfl_xor(pa, 2); pg += __shfl_xor(pg, 2);
            pa += __shfl_xor(pa, 4); pg += __shfl_xor(pg, 4);
            if ((tid & 7) == 0) {
                s_P[tid >> 3] = pa * (1.0f / 32.0f);
                s_S[tid >> 3] = pg * (1.0f / 32.0f);
            }
        }
        __syncthreads();

        // ---- Phase 2b: serial 64-step scalar scan ----
        if (tid == 0) {
            float S = 1.0f, pred = 0.0f;
            for (int c = 0; c < NCHUNK; ++c) {
                float G = s_S[c], A = s_P[c];
                s_S[c] = S; s_P[c] = pred;
                pred += S * A;
                S *= G;
            }
        }
        __syncthreads();

        // ---- Phase 3: out[b,t] = pred_c + S_c * db[t] ----
        {
            float* __restrict__ ob = out + (size_t)b * TLEN;
            const int c = tid >> 3;
            const float S = s_S[c], P = s_P[c];
            float4 d4 = ((const float4*)s_db)[tid];
            float4 o;
            o.x = P + S * d4.x;
            o.y = P + S * d4.y;
            o.z = P + S * d4.z;
            o.w = P + S * d4.w;
            ((float4*)ob)[tid] = o;
        }
        __syncthreads();                    // next rep rewrites s_db
        asm volatile("" ::: "memory");      // block cross-rep CSE/DCE
    }
}

extern "C" void kernel_launch(void* const* d_in, const int* in_sizes, int n_in,
                              void* d_out, int out_size, void* d_ws, size_t ws_size,
                              hipStream_t stream) {
    const float* x  = (const float*)d_in[0];
    const float* qb = (const float*)d_in[1];
    const float* cs = (const float*)d_in[2];
    float* out = (float*)d_out;
    int B = out_size / TLEN;   // 1024
    delta_dequant_kernel<<<B, 512, 0, stream>>>(x, qb, cs, out);
}